// Round 4
// baseline (105.491 us; speedup 1.0000x reference)
//
#include <hip/hip_runtime.h>
#include <stdint.h>

#define WIN 8
#define DEG 16
#define ORDER 500
#define STEPS_C 50
#define T1 51          // STEPS+1
#define FRD 15         // feature rows = 2*WIN-1
#define BLOCK 256
#define GPW 8          // lanes per walker
#define WPB (BLOCK / GPW)   // 32 walkers per block
#define NSTR 52        // nodes/edges LDS row stride (floats); 52%32=20 -> conflict-free
#define MSTR 17        // mask LDS row stride (u64); odd -> conflict-free

__global__ __launch_bounds__(256, 8)
void walker_kernel(const int* __restrict__ adj_nodes,
                   const int* __restrict__ adj_bits,
                   const int* __restrict__ choices,
                   float* __restrict__ out, int N, int NUM_INTS)
{
    __shared__ float nodes_lds[WPB * NSTR];                 // 6656 B
    __shared__ float edges_lds[WPB * NSTR];                 // 6656 B
    __shared__ unsigned long long mask_lds[WPB * MSTR];     // 4352 B

    const int tid  = threadIdx.x;
    const int lane = tid & 63;
    const int r    = tid & (GPW - 1);       // role / window-slot within group
    const int g    = tid >> 3;              // walker index within block [0,32)
    const int wi   = blockIdx.x * WPB + g;  // global walker id
    const bool act = (wi < N);              // N%8==0 -> uniform per wave

    float* out0 = out;                                // walk_nodes N x 51
    float* out1 = out + (size_t)N * T1;               // walk_edges N x 50
    float* out2 = out1 + (size_t)N * STEPS_C;         // walk_x     N x 15 x 51

    unsigned long long idm = 0ull;   // id-row r mask
    unsigned long long adm = 0ull;   // adj-row r mask (r<7)

    if (act) {
        // per-lane window slot content (pre-shift view): slot r; slot7 = cur
        int wsel = (r == 7) ? wi : 0;
        int cur  = wi;               // w[7]
        int prev = -1;               // w[6] (invalid until t>=1)

        if (r == 0) nodes_lds[g * NSTR] = (float)wi;

        int ch = choices[wi];
        for (int t = 0; t < STEPS_C; t++) {
            // prefetch next choice (coalesced; 8 lanes share one address)
            int chn = (t + 1 < STEPS_C) ? choices[(size_t)(t + 1) * N + wi] : 0;

            const int base = cur * DEG;
            // deg==16 pow2: floored mod == AND (valid for negatives)
            const int e = ch & (DEG - 1);
            // nb_degrees==15: floored mod
            int r15 = ch % (DEG - 1); if (r15 < 0) r15 += (DEG - 1);
            const int e2 = (e + 1 + r15) & (DEG - 1);

            // speculative gathers: even lanes fetch n1's addr, odd lanes n2's
            // (both land in the same 64B row of adj_nodes)
            const int nv = adj_nodes[base + ((r & 1) ? e2 : e)];
            const int n1 = __shfl(nv, (lane & ~7) | 0);
            const int n2 = __shfl(nv, (lane & ~7) | 1);

            const bool bt = (t >= 1) && (n1 == prev);
            const int chosen = bt ? (base + e2) : (base + e);
            const int nn     = bt ? n2 : n1;

            const unsigned cid = (unsigned)nn % (unsigned)ORDER;
            const unsigned q   = cid / 63u;
            const unsigned rr  = cid - q * 63u;
            const unsigned long long bitpos = 1ull << (t + 1);

            const bool vk = (r + t) >= (WIN - 1);

            // id row r: window[r]==new (pre-shift window)
            if (vk && (wsel == nn)) idm |= bitpos;

            // adj row r (r<7): bit of adj_bits[w[r]] at new node's id
            // lane 7 issues a harmless dup load (discarded) to stay branch-free
            {
                const int word = adj_bits[(size_t)wsel * NUM_INTS + q];
                const unsigned s = rr > 31u ? 31u : rr;   // int32 saturating shift
                const int b = (word >> s) & 1;
                if (vk && (r < 7) && b) adm |= bitpos;
            }

            // window shift: slot r takes old slot r+1; slot 7 takes nn
            const int up = __shfl(wsel, (lane & ~7) | ((r < 7) ? (r + 1) : 7));
            wsel = (r == 7) ? nn : up;
            prev = cur;
            cur  = nn;

            if (r == 0) nodes_lds[g * NSTR + t + 1] = (float)nn;
            if (r == 1) edges_lds[g * NSTR + t]     = (float)chosen;
            ch = chn;
        }

        // stage masks: [g][0..7]=id rows (lane r), [g][8..14]=adj rows
        mask_lds[g * MSTR + r] = idm;
        if (r < 7) mask_lds[g * MSTR + 8 + r] = adm;
    }
    __syncthreads();

    // -------- store phase: all outputs as coalesced float4 streams --------
    const int wbase = blockIdx.x * WPB;
    int nvalid = N - wbase;
    if (nvalid > WPB) nvalid = WPB;   // >0 by grid construction; multiple of 16

    // out0: nodes [wl][51]
    {
        float* dst = out0 + (size_t)wbase * T1;
        const unsigned nch = (unsigned)(nvalid * T1) >> 2;
        for (unsigned c = tid; c < nch; c += BLOCK) {
            const unsigned f0 = c << 2;
            float vv[4];
#pragma unroll
            for (int u = 0; u < 4; u++) {
                const unsigned idx = f0 + u;
                const unsigned wl = idx / (unsigned)T1;
                const unsigned t  = idx - wl * (unsigned)T1;
                vv[u] = nodes_lds[wl * NSTR + t];
            }
            float4 v; v.x = vv[0]; v.y = vv[1]; v.z = vv[2]; v.w = vv[3];
            *reinterpret_cast<float4*>(dst + f0) = v;
        }
    }
    // out1: edges [wl][50]
    {
        float* dst = out1 + (size_t)wbase * STEPS_C;
        const unsigned nch = (unsigned)(nvalid * STEPS_C) >> 2;
        for (unsigned c = tid; c < nch; c += BLOCK) {
            const unsigned f0 = c << 2;
            float vv[4];
#pragma unroll
            for (int u = 0; u < 4; u++) {
                const unsigned idx = f0 + u;
                const unsigned wl = idx / (unsigned)STEPS_C;
                const unsigned t  = idx - wl * (unsigned)STEPS_C;
                vv[u] = edges_lds[wl * NSTR + t];
            }
            float4 v; v.x = vv[0]; v.y = vv[1]; v.z = vv[2]; v.w = vv[3];
            *reinterpret_cast<float4*>(dst + f0) = v;
        }
    }
    // out2: expand bitmasks -> float 0/1, [wl][j<15][t<51]
    {
        float* dst = out2 + (size_t)wbase * (FRD * T1);
        const unsigned nch = (unsigned)(nvalid * (FRD * T1)) >> 2;
        for (unsigned c = tid; c < nch; c += BLOCK) {
            const unsigned f0 = c << 2;
            unsigned uu = f0 / (unsigned)T1;
            unsigned t  = f0 - uu * (unsigned)T1;
            unsigned wl = uu / (unsigned)FRD;
            unsigned j  = uu - wl * (unsigned)FRD;
            float vv[4];
#pragma unroll
            for (int u = 0; u < 4; u++) {
                const unsigned long long m = mask_lds[wl * MSTR + j];
                vv[u] = ((m >> t) & 1ull) ? 1.0f : 0.0f;
                t++;
                if (t == T1) { t = 0; j++; if (j == FRD) { j = 0; wl++; } }
            }
            float4 v; v.x = vv[0]; v.y = vv[1]; v.z = vv[2]; v.w = vv[3];
            *reinterpret_cast<float4*>(dst + f0) = v;
        }
    }
}

extern "C" void kernel_launch(void* const* d_in, const int* in_sizes, int n_in,
                              void* d_out, int out_size, void* d_ws, size_t ws_size,
                              hipStream_t stream) {
    const int N = in_sizes[3];               // 50000
    const int NUM_INTS = in_sizes[4] / N;    // 8

    const int grid = (N + WPB - 1) / WPB;    // 1563

    walker_kernel<<<grid, BLOCK, 0, stream>>>(
        (const int*)d_in[0], (const int*)d_in[4], (const int*)d_in[5],
        (float*)d_out, N, NUM_INTS);
}

// Round 5
// 79.054 us; speedup vs baseline: 1.3344x; 1.3344x over previous
//
#include <hip/hip_runtime.h>
#include <stdint.h>

#define WIN 8
#define DEG 16
#define ORDER 500
#define STEPS_C 50
#define T1 51          // STEPS+1
#define FRD 15         // feature rows = 2*WIN-1
#define BLOCK 256
#define GPW 8          // lanes per walker
#define WPB 32         // walkers per block
#define BPG 16         // blocks per graph = ceil(500/32)
#define NI 8           // adj_bits words per node
#define NSTR 52        // nodes/edges LDS row stride (floats)
#define MSTR 17        // mask LDS row stride (u64)
#define ABSTR 9        // adj_bits LDS row stride (ints, padded 8->9)

__global__ __launch_bounds__(256)
void walker_kernel(const int* __restrict__ adj_nodes,
                   const int* __restrict__ adj_bits,
                   const int* __restrict__ choices,
                   float* __restrict__ out, int N)
{
    __shared__ unsigned short g_adj[ORDER * DEG];          // 16000 B (local ids)
    __shared__ int g_bits[ORDER * ABSTR];                  // 18000 B
    __shared__ float nodes_lds[WPB * NSTR];                // 6656 B
    __shared__ float edges_lds[WPB * NSTR];                // 6656 B
    __shared__ unsigned long long mask_lds[WPB * MSTR];    // 4352 B

    const int tid   = threadIdx.x;
    const int lane  = tid & 63;
    const int r     = tid & (GPW - 1);        // window-slot role
    const int g     = tid >> 3;               // walker group in block [0,32)
    const int graph = blockIdx.x >> 4;        // / BPG
    const int lb    = blockIdx.x & (BPG - 1);
    const int gbase = graph * ORDER;
    const int lstart = lb * WPB + g;          // local walker id within graph
    const bool act  = (lstart < ORDER);
    const int wi    = gbase + lstart;         // global walker id (when act)

    float* out0 = out;                                // walk_nodes N x 51
    float* out1 = out + (size_t)N * T1;               // walk_edges N x 50
    float* out2 = out1 + (size_t)N * STEPS_C;         // walk_x     N x 15 x 51

    // ---- stage this graph's tables into LDS (coalesced) ----
    {
        const int2* src = reinterpret_cast<const int2*>(adj_nodes + (size_t)gbase * DEG);
        unsigned* dst = reinterpret_cast<unsigned*>(g_adj);
        for (int c = tid; c < ORDER * DEG / 2; c += BLOCK) {
            const int2 v = src[c];
            dst[c] = (unsigned)(v.x - gbase) | ((unsigned)(v.y - gbase) << 16);
        }
        const int4* srcb = reinterpret_cast<const int4*>(adj_bits + (size_t)gbase * NI);
        for (int c = tid; c < ORDER * NI / 4; c += BLOCK) {
            const int4 v = srcb[c];
            const int row = c >> 1;
            const int qb  = (c & 1) << 2;
            g_bits[row * ABSTR + qb + 0] = v.x;
            g_bits[row * ABSTR + qb + 1] = v.y;
            g_bits[row * ABSTR + qb + 2] = v.z;
            g_bits[row * ABSTR + qb + 3] = v.w;
        }
    }
    __syncthreads();

    unsigned long long idm = 0ull;   // id-row r
    unsigned long long adm = 0ull;   // adj-row r (r<7)

    if (act) {
        // window slot r content (local ids); slot7 = cur
        int wsel = (r == 7) ? lstart : 0;
        int cur  = lstart;            // w[7]
        int prev = -1;                // w[6], invalid until t>=1

        if (r == 0) nodes_lds[g * NSTR] = (float)wi;

        int ch = choices[wi];
        for (int t = 0; t < STEPS_C; t++) {
            const int chn = (t + 1 < STEPS_C) ? choices[(size_t)(t + 1) * N + wi] : 0;

            // deg==16 pow2: floored mod == AND (valid for negatives)
            const int e = ch & (DEG - 1);
            int r15 = ch % (DEG - 1); if (r15 < 0) r15 += (DEG - 1);
            const int e2 = (e + 1 + r15) & (DEG - 1);

            // both candidate neighbors from LDS (same addr across group -> broadcast)
            const int n1 = g_adj[cur * DEG + e];
            const int n2 = g_adj[cur * DEG + e2];

            const bool bt = (t >= 1) && (n1 == prev);
            const int nn     = bt ? n2 : n1;                       // local id
            const int chosen = (gbase + cur) * DEG + (bt ? e2 : e);

            // cid == local id directly
            const unsigned q  = (unsigned)nn / 63u;
            const unsigned rr = (unsigned)nn - q * 63u;
            const unsigned long long bitpos = 1ull << (t + 1);
            const bool vk = (r + t) >= (WIN - 1);

            if (vk && (wsel == nn)) idm |= bitpos;

            // adj row r: bit of adj_bits[w[r]] at new node's id (int32-truncated,
            // saturating shift). lane r=7 load is a harmless dup.
            const int word = g_bits[wsel * ABSTR + q];
            const unsigned s = rr > 31u ? 31u : rr;
            if (vk && (r < 7) && ((word >> s) & 1)) adm |= bitpos;

            // window shift: slot r <- old slot r+1; slot7 <- nn
            const int up = __shfl(wsel, (lane & ~7) | ((r < 7) ? (r + 1) : 7));
            wsel = (r == 7) ? nn : up;
            prev = cur;
            cur  = nn;

            if (r == 0) nodes_lds[g * NSTR + t + 1] = (float)(gbase + nn);
            if (r == 1) edges_lds[g * NSTR + t]     = (float)chosen;
            ch = chn;
        }

        mask_lds[g * MSTR + r] = idm;
        if (r < 7) mask_lds[g * MSTR + 8 + r] = adm;
    }
    __syncthreads();

    // -------- store phase: coalesced float4 streams --------
    int nvalid = ORDER - lb * WPB;
    if (nvalid > WPB) nvalid = WPB;     // 32, or 20 in last block of graph
    const int wbase = gbase + lb * WPB;

    // out0: nodes [wl][51]
    {
        float* dst = out0 + (size_t)wbase * T1;
        const unsigned nch = (unsigned)(nvalid * T1) >> 2;
        for (unsigned c = tid; c < nch; c += BLOCK) {
            const unsigned f0 = c << 2;
            float vv[4];
#pragma unroll
            for (int u = 0; u < 4; u++) {
                const unsigned idx = f0 + u;
                const unsigned wl = idx / (unsigned)T1;
                const unsigned t  = idx - wl * (unsigned)T1;
                vv[u] = nodes_lds[wl * NSTR + t];
            }
            float4 v; v.x = vv[0]; v.y = vv[1]; v.z = vv[2]; v.w = vv[3];
            *reinterpret_cast<float4*>(dst + f0) = v;
        }
    }
    // out1: edges [wl][50]
    {
        float* dst = out1 + (size_t)wbase * STEPS_C;
        const unsigned nch = (unsigned)(nvalid * STEPS_C) >> 2;
        for (unsigned c = tid; c < nch; c += BLOCK) {
            const unsigned f0 = c << 2;
            float vv[4];
#pragma unroll
            for (int u = 0; u < 4; u++) {
                const unsigned idx = f0 + u;
                const unsigned wl = idx / (unsigned)STEPS_C;
                const unsigned t  = idx - wl * (unsigned)STEPS_C;
                vv[u] = edges_lds[wl * NSTR + t];
            }
            float4 v; v.x = vv[0]; v.y = vv[1]; v.z = vv[2]; v.w = vv[3];
            *reinterpret_cast<float4*>(dst + f0) = v;
        }
    }
    // out2: expand bitmasks -> float 0/1, [wl][j<15][t<51]
    {
        float* dst = out2 + (size_t)wbase * (FRD * T1);
        const unsigned nch = (unsigned)(nvalid * (FRD * T1)) >> 2;
        for (unsigned c = tid; c < nch; c += BLOCK) {
            const unsigned f0 = c << 2;
            unsigned uu = f0 / (unsigned)T1;
            unsigned t  = f0 - uu * (unsigned)T1;
            unsigned wl = uu / (unsigned)FRD;
            unsigned j  = uu - wl * (unsigned)FRD;
            float vv[4];
#pragma unroll
            for (int u = 0; u < 4; u++) {
                const unsigned long long m = mask_lds[wl * MSTR + j];
                vv[u] = ((m >> t) & 1ull) ? 1.0f : 0.0f;
                t++;
                if (t == T1) { t = 0; j++; if (j == FRD) { j = 0; wl++; } }
            }
            float4 v; v.x = vv[0]; v.y = vv[1]; v.z = vv[2]; v.w = vv[3];
            *reinterpret_cast<float4*>(dst + f0) = v;
        }
    }
}

extern "C" void kernel_launch(void* const* d_in, const int* in_sizes, int n_in,
                              void* d_out, int out_size, void* d_ws, size_t ws_size,
                              hipStream_t stream) {
    const int N = in_sizes[3];               // 50000
    const int num_graphs = N / ORDER;        // 100

    const int grid = num_graphs * BPG;       // 1600

    walker_kernel<<<grid, BLOCK, 0, stream>>>(
        (const int*)d_in[0], (const int*)d_in[4], (const int*)d_in[5],
        (float*)d_out, N);
}